// Round 11
// baseline (912.085 us; speedup 1.0000x reference)
//
#include <hip/hip_runtime.h>

#define B_ 512
#define T_ 512
#define F_ 128
#define H_ 32
#define C_ 6
#define CH 32            // timesteps per chunk
#define NCH (T_ / CH)    // 16 chunks

// ---------------------------------------------------------------------------
// Fused LSTM, barrier-scheduled pipeline. 256 blocks x 384 threads (6 waves).
// Block b owns batch rows {2b, 2b+1}.
//   waves 0,1: scan consumers (row 2b / 2b+1)  [round-8 verified math]
//   waves 2,3: producers row 2b   (cols 0-63 / 64-127)
//   waves 4,5: producers row 2b+1
// Static schedule, one __syncthreads per phase, consumer one chunk behind:
//   phase ph: producers matvec chunk ph -> zring[ph&1], stage chunk ph+1 x
//             -> xst[(ph+1)&1]; consumers scan chunk ph-1 <- zring[(ph-1)&1].
// Slot parities never collide; the barrier stops any wave racing a full
// phase ahead. mring is un-slotted (4 KB) -- no reuse, no parity race.
// Both role paths execute exactly NCH+1 barriers (wave-uniform branch).
//
// ROUND-11 FIX: __launch_bounds__(384, 1).  Round 10's (384, 2) capped the
// allocator at 128 VGPRs (occupancy granularity step), spilling the
// producer's Wc[128] to scratch -> 141 MB of scratch writes, 905 us.  With
// min-1-wave/EU the budget is 256 VGPRs; producer (~180) fits, no spill.
// Occupancy is LDS-bound at 1 block/CU (132 KB) regardless, 256 blocks =
// 256 CUs.
// ---------------------------------------------------------------------------

__device__ __forceinline__ float sigmf(float xx) {
  return __builtin_amdgcn_rcpf(1.f + __expf(-xx));
}
__device__ __forceinline__ float tanhf_(float xx) {
  return __builtin_amdgcn_rcpf(1.f + __expf(-2.f * xx)) * 2.f - 1.f;
}

__global__ __launch_bounds__(384, 1) void k_fused(
    const float* __restrict__ x, const float* __restrict__ Wx,
    const float* __restrict__ bias, const float* __restrict__ Wh,
    const float* __restrict__ Wfc, const float* __restrict__ bfc,
    float* __restrict__ out)
{
  __shared__ float zring[2][2][CH][128];   // 64 KB [row][slot][t][col]
  __shared__ float xst  [2][2][CH][128];   // 64 KB [row][slot][t][f]
  __shared__ float mring[2][NCH][CH];      // 4 KB  [row][chunk][t]  (no reuse)

  const int tid  = threadIdx.x;
  const int wid  = tid >> 6;
  const int lane = tid & 63;
  const int brow = blockIdx.x * 2;

  if (wid >= 2) {
    // ------------------------------ producer ------------------------------
    const int p    = wid - 2;
    const int prow = p >> 1;
    const int hp   = p & 1;
    const int cb   = hp * 64;        // owned column range [cb, cb+64)
    const int sb   = hp * 16;        // staged timestep range [sb, sb+16)
    const int r    = brow + prow;

    float Wc[128];                   // Wx column (cb+lane), register-resident
#pragma unroll
    for (int f = 0; f < 128; ++f) Wc[f] = Wx[f * 128 + cb + lane];
    const float bb = bias[cb + lane];
    const float* xr = x + (size_t)r * (T_ * F_);

    // prologue: load + stage chunk 0 into xst[prow][0] and mring[prow][0]
    float2 xld[16];
#pragma unroll
    for (int s = 0; s < 16; ++s)
      xld[s] = *(const float2*)(xr + (sb + s) * F_ + 2 * lane);
#pragma unroll
    for (int s = 0; s < 16; ++s) {
      *(float2*)(&xst[prow][0][sb + s][2 * lane]) = xld[s];
      const bool nb = (xld[s].x != 0.f) || (xld[s].y != 0.f);
      const unsigned long long bal = __ballot(nb);
      if (lane == 0) mring[prow][0][sb + s] = bal ? 1.f : 0.f;
    }

    for (int ph = 0; ph <= NCH; ++ph) {
      __syncthreads();
      if (ph >= NCH) continue;       // last phase: consumers finish chunk 15
      const int slot = ph & 1;

      // issue next chunk's global loads early (latency hides under matvec)
      if (ph + 1 < NCH) {
#pragma unroll
        for (int s = 0; s < 16; ++s)
          xld[s] = *(const float2*)(xr + ((ph + 1) * CH + sb + s) * F_ + 2 * lane);
      }

      // matvec chunk ph: z[t][cb+lane] = bias + sum_f xst[t][f] * Wc[f]
      for (int t = 0; t < CH; ++t) {
        float z0 = bb, z1 = 0.f, z2 = 0.f, z3 = 0.f;
        const float* xp = &xst[prow][slot][t][0];
#pragma unroll
        for (int fq = 0; fq < 32; ++fq) {
          const float4 xf = *(const float4*)(xp + fq * 4);  // uniform broadcast
          z0 += xf.x * Wc[fq * 4 + 0];
          z1 += xf.y * Wc[fq * 4 + 1];
          z2 += xf.z * Wc[fq * 4 + 2];
          z3 += xf.w * Wc[fq * 4 + 3];
        }
        zring[prow][slot][t][cb + lane] = (z0 + z1) + (z2 + z3);
      }

      // stage chunk ph+1 into the other slot (read next phase, post-barrier)
      if (ph + 1 < NCH) {
#pragma unroll
        for (int s = 0; s < 16; ++s) {
          *(float2*)(&xst[prow][slot ^ 1][sb + s][2 * lane]) = xld[s];
          const bool nb = (xld[s].x != 0.f) || (xld[s].y != 0.f);
          const unsigned long long bal = __ballot(nb);
          if (lane == 0) mring[prow][ph + 1][sb + s] = bal ? 1.f : 0.f;
        }
      }
    }
    return;
  }

  // ------------------------------ consumer ------------------------------
  const int row  = wid;
  const int r    = brow + row;
  const int half = lane >> 5;
  const int j    = lane & 31;
  const int colA = half * 32 + j;        // i (half0) / f (half1)
  const int colB = 64 + half * 32 + j;   // g (half0) / o (half1)

  float WhA[32], WhB[32];
#pragma unroll
  for (int f = 0; f < 32; ++f) {
    WhA[f] = Wh[f * 128 + colA];
    WhB[f] = Wh[f * 128 + colB];
  }

  float hsc[32];                         // wave-uniform (SGPR via readlane)
#pragma unroll
  for (int f = 0; f < 32; ++f) hsc[f] = 0.f;
  float cj = 0.f, hj = 0.f;

  for (int ph = 0; ph <= NCH; ++ph) {
    __syncthreads();
    if (ph < 1) continue;                // phase 0: producers fill chunk 0
    const int c    = ph - 1;
    const int slot = c & 1;
    const float* zb = &zring[row][slot][0][0];
    const float* mb = &mring[row][c][0];

    // depth-4 register prefetch ring (statically indexed)
    float za[4], zc[4], mm[4];
#pragma unroll
    for (int u = 0; u < 4; ++u) {
      za[u] = zb[u * 128 + colA];
      zc[u] = zb[u * 128 + colB];
      mm[u] = mb[u];
    }
    for (int s0 = 0; s0 < 8; ++s0) {
#pragma unroll
      for (int u = 0; u < 4; ++u) {
        const int s = s0 * 4 + u;
        float zA0 = za[u], zA1 = 0.f;
        float zB0 = zc[u], zB1 = 0.f;
        const float m = mm[u];
        if (s0 < 7) {                    // refill slot u with step s+4
          za[u] = zb[(s + 4) * 128 + colA];
          zc[u] = zb[(s + 4) * 128 + colB];
          mm[u] = mb[s + 4];
        }
        // recurrent matvec: 64 v_fmac (sgpr*vgpr), 4 independent chains
#pragma unroll
        for (int f = 0; f < 16; ++f) {
          zA0 += hsc[2 * f]     * WhA[2 * f];
          zA1 += hsc[2 * f + 1] * WhA[2 * f + 1];
          zB0 += hsc[2 * f]     * WhB[2 * f];
          zB1 += hsc[2 * f + 1] * WhB[2 * f + 1];
        }
        const float zA = zA0 + zA1;           // half0: zi, half1: zf
        const float zB = zB0 + zB1;           // half0: zg, half1: zo
        const float oA = __shfl_xor(zA, 32);
        const float oB = __shfl_xor(zB, 32);
        const float zi = half ? oA : zA;
        const float zf = half ? zA : oA;
        const float zg = half ? oB : zB;
        const float zo = half ? zB : oB;

        const float ig = sigmf(zi);
        const float fg = sigmf(zf);
        const float gg = tanhf_(zg);
        const float og = sigmf(zo);
        const float cn = fg * cj + ig * gg;
        const float hn = og * tanhf_(cn);
        cj += m * (cn - cj);          // masked: keep previous state if m==0
        hj += m * (hn - hj);

        // broadcast h: 32 independent v_readlane -> uniform scalars
#pragma unroll
        for (int f = 0; f < 32; ++f)
          hsc[f] = __uint_as_float(__builtin_amdgcn_readlane(__float_as_uint(hj), f));
      }
    }
  }

  // FC + softmax (all lanes redundant from uniform h; lane 0 writes)
  float logits[C_];
#pragma unroll
  for (int c = 0; c < C_; ++c) {
    float aa = bfc[c];
#pragma unroll
    for (int f = 0; f < 32; ++f) aa += hsc[f] * Wfc[f * C_ + c];
    logits[c] = aa;
  }
  if (lane == 0) {
    float mx = logits[0];
#pragma unroll
    for (int c = 1; c < C_; ++c) mx = fmaxf(mx, logits[c]);
    float e[C_], sden = 0.f;
#pragma unroll
    for (int c = 0; c < C_; ++c) { e[c] = __expf(logits[c] - mx); sden += e[c]; }
    const float rs = 1.f / sden;
#pragma unroll
    for (int c = 0; c < C_; ++c) out[(size_t)r * C_ + c] = e[c] * rs;
  }
}

// ---------------------------------------------------------------------------
extern "C" void kernel_launch(void* const* d_in, const int* in_sizes, int n_in,
                              void* d_out, int out_size, void* d_ws, size_t ws_size,
                              hipStream_t stream) {
  const float* x   = (const float*)d_in[0];
  const float* Wx  = (const float*)d_in[1];
  const float* Wh  = (const float*)d_in[2];
  const float* bv  = (const float*)d_in[3];
  const float* Wfc = (const float*)d_in[4];
  const float* bfc = (const float*)d_in[5];
  float* out = (float*)d_out;

  k_fused<<<B_ / 2, 384, 0, stream>>>(x, Wx, bv, Wh, Wfc, bfc, out);
}

// Round 12
// 535.193 us; speedup vs baseline: 1.7042x; 1.7042x over previous
//
#include <hip/hip_runtime.h>

#define B_ 512
#define T_ 512
#define F_ 128
#define H_ 32
#define C_ 6
#define CH 16            // timesteps per chunk
#define NCH (T_ / CH)    // 32 chunks

// ---------------------------------------------------------------------------
// Fused LSTM, barrier-scheduled pipeline, f-split producers.
// 512 blocks x 320 threads (5 waves); block owns ONE batch row.
//   wave 0: scan consumer (round-8 verified math)
//   waves 1-4: producers; wave p owns quadrant (fhalf = p>>1, colhalf = p&1):
//     64 weights/lane (f in [fh*64,+64), col = ch*64+lane)  -> NO SPILL
//     (round 10/11: 128-weight columns forced 141 MB of scratch traffic at
//      the allocator's 128-VGPR occupancy step; f-split fits under it)
// Producers write f-partials zpart[fh]; the CONSUMER adds the two partials
// (2 extra LDS loads + 2 adds per step) -- no producer-combine sync.
// Schedule (one __syncthreads per phase, depth-2):
//   phase ph: producers matvec chunk ph from xst[ph&1] -> zpart[*][ph&1],
//             stage chunk ph+1 x -> xst[(ph+1)&1] (loads issued early);
//             consumer scans chunk ph-1 from zpart[*][(ph-1)&1].
// Slot parities never collide (verified round 10). mring un-slotted.
// LDS = 50 KB -> 2 blocks/CU, all 512 blocks resident.
// ---------------------------------------------------------------------------

__device__ __forceinline__ float sigmf(float xx) {
  return __builtin_amdgcn_rcpf(1.f + __expf(-xx));
}
__device__ __forceinline__ float tanhf_(float xx) {
  return __builtin_amdgcn_rcpf(1.f + __expf(-2.f * xx)) * 2.f - 1.f;
}

__global__ __launch_bounds__(320) void k_fused(
    const float* __restrict__ x, const float* __restrict__ Wx,
    const float* __restrict__ bias, const float* __restrict__ Wh,
    const float* __restrict__ Wfc, const float* __restrict__ bfc,
    float* __restrict__ out)
{
  __shared__ float xst[2][CH * 128];        // 16 KB [slot][t*128+f]
  __shared__ float zpart[2][2][CH * 128];   // 32 KB [fhalf][slot][t*128+col]
  __shared__ float mring[NCH][CH];          // 2 KB  (no reuse, no parity risk)

  const int tid  = threadIdx.x;
  const int wid  = tid >> 6;
  const int lane = tid & 63;
  const int row  = blockIdx.x;

  if (wid >= 1) {
    // ------------------------------ producer ------------------------------
    const int p    = wid - 1;        // 0..3
    const int fh   = p >> 1;         // f-half
    const int chf  = p & 1;          // col-half
    const int fb   = fh * 64;
    const int cb   = chf * 64;
    const int ptid = tid - 64;       // 0..255 across the 4 producer waves
    const int tloc = ptid >> 4;      // this lane's staged timestep (0..15)
    const int g    = lane >> 4;      // ballot group within wave

    float Wc[64];                    // quadrant weights: col cb+lane, f fb..fb+63
#pragma unroll
    for (int f = 0; f < 64; ++f) Wc[f] = Wx[(size_t)(fb + f) * 128 + cb + lane];
    const float bb = (fh == 0) ? bias[cb + lane] : 0.f;

    const float* xr = x + (size_t)row * (T_ * F_);

    // prologue: load + stage chunk 0
    float4 xl0 = *(const float4*)(xr + ptid * 8);
    float4 xl1 = *(const float4*)(xr + ptid * 8 + 4);
    *(float4*)(&xst[0][ptid * 8])     = xl0;
    *(float4*)(&xst[0][ptid * 8 + 4]) = xl1;
    {
      const bool nz = (xl0.x != 0.f) || (xl0.y != 0.f) || (xl0.z != 0.f) || (xl0.w != 0.f)
                   || (xl1.x != 0.f) || (xl1.y != 0.f) || (xl1.z != 0.f) || (xl1.w != 0.f);
      const unsigned long long bal = __ballot(nz);
      if ((lane & 15) == 0)
        mring[0][tloc] = ((bal >> (g * 16)) & 0xFFFFull) ? 1.f : 0.f;
    }

    for (int ph = 0; ph <= NCH; ++ph) {
      __syncthreads();
      if (ph >= NCH) continue;
      const int slot = ph & 1;

      // issue next chunk's global loads early (latency hides under matvec)
      if (ph + 1 < NCH) {
        xl0 = *(const float4*)(xr + (ph + 1) * (CH * 128) + ptid * 8);
        xl1 = *(const float4*)(xr + (ph + 1) * (CH * 128) + ptid * 8 + 4);
      }

      // matvec chunk ph: zpart[fh][slot][t][cb+lane] = bb + sum_{f-half} x*W
      for (int t = 0; t < CH; ++t) {
        float z0 = bb, z1 = 0.f, z2 = 0.f, z3 = 0.f;
        const float* xp = &xst[slot][t * 128 + fb];
#pragma unroll
        for (int fq = 0; fq < 16; ++fq) {
          const float4 xf = *(const float4*)(xp + fq * 4);   // uniform broadcast
          z0 += xf.x * Wc[fq * 4 + 0];
          z1 += xf.y * Wc[fq * 4 + 1];
          z2 += xf.z * Wc[fq * 4 + 2];
          z3 += xf.w * Wc[fq * 4 + 3];
        }
        zpart[fh][slot][t * 128 + cb + lane] = (z0 + z1) + (z2 + z3);
      }

      // stage chunk ph+1 into the other slot (read next phase, post-barrier)
      if (ph + 1 < NCH) {
        *(float4*)(&xst[slot ^ 1][ptid * 8])     = xl0;
        *(float4*)(&xst[slot ^ 1][ptid * 8 + 4]) = xl1;
        const bool nz = (xl0.x != 0.f) || (xl0.y != 0.f) || (xl0.z != 0.f) || (xl0.w != 0.f)
                     || (xl1.x != 0.f) || (xl1.y != 0.f) || (xl1.z != 0.f) || (xl1.w != 0.f);
        const unsigned long long bal = __ballot(nz);
        if ((lane & 15) == 0)
          mring[ph + 1][tloc] = ((bal >> (g * 16)) & 0xFFFFull) ? 1.f : 0.f;
      }
    }
    return;
  }

  // ------------------------------ consumer ------------------------------
  const int half = lane >> 5;
  const int j    = lane & 31;
  const int colA = half * 32 + j;        // i (half0) / f (half1)
  const int colB = 64 + half * 32 + j;   // g (half0) / o (half1)

  float WhA[32], WhB[32];
#pragma unroll
  for (int f = 0; f < 32; ++f) {
    WhA[f] = Wh[f * 128 + colA];
    WhB[f] = Wh[f * 128 + colB];
  }

  float hsc[32];                         // wave-uniform (SGPR via readlane)
#pragma unroll
  for (int f = 0; f < 32; ++f) hsc[f] = 0.f;
  float cj = 0.f, hj = 0.f;

  for (int ph = 0; ph <= NCH; ++ph) {
    __syncthreads();
    if (ph < 1) continue;                // phase 0: producers fill chunk 0
    const int c    = ph - 1;
    const int slot = c & 1;
    const float* z0p = &zpart[0][slot][0];
    const float* z1p = &zpart[1][slot][0];
    const float* mb  = &mring[c][0];

    // depth-4 register prefetch ring over the 16-step chunk
    float za[4], zc[4], mm[4];
#pragma unroll
    for (int u = 0; u < 4; ++u) {
      za[u] = z0p[u * 128 + colA] + z1p[u * 128 + colA];
      zc[u] = z0p[u * 128 + colB] + z1p[u * 128 + colB];
      mm[u] = mb[u];
    }
    for (int s0 = 0; s0 < 4; ++s0) {
#pragma unroll
      for (int u = 0; u < 4; ++u) {
        const int s = s0 * 4 + u;
        float zA0 = za[u], zA1 = 0.f;
        float zB0 = zc[u], zB1 = 0.f;
        const float m = mm[u];
        if (s0 < 3) {                    // refill slot u with step s+4
          za[u] = z0p[(s + 4) * 128 + colA] + z1p[(s + 4) * 128 + colA];
          zc[u] = z0p[(s + 4) * 128 + colB] + z1p[(s + 4) * 128 + colB];
          mm[u] = mb[s + 4];
        }
        // recurrent matvec: 64 v_fmac (sgpr*vgpr), 4 independent chains
#pragma unroll
        for (int f = 0; f < 16; ++f) {
          zA0 += hsc[2 * f]     * WhA[2 * f];
          zA1 += hsc[2 * f + 1] * WhA[2 * f + 1];
          zB0 += hsc[2 * f]     * WhB[2 * f];
          zB1 += hsc[2 * f + 1] * WhB[2 * f + 1];
        }
        const float zA = zA0 + zA1;           // half0: zi, half1: zf
        const float zB = zB0 + zB1;           // half0: zg, half1: zo
        const float oA = __shfl_xor(zA, 32);
        const float oB = __shfl_xor(zB, 32);
        const float zi = half ? oA : zA;
        const float zf = half ? zA : oA;
        const float zg = half ? oB : zB;
        const float zo = half ? zB : oB;

        const float ig = sigmf(zi);
        const float fg = sigmf(zf);
        const float gg = tanhf_(zg);
        const float og = sigmf(zo);
        const float cn = fg * cj + ig * gg;
        const float hn = og * tanhf_(cn);
        cj += m * (cn - cj);          // masked: keep previous state if m==0
        hj += m * (hn - hj);

        // broadcast h: 32 independent v_readlane -> uniform scalars
#pragma unroll
        for (int f = 0; f < 32; ++f)
          hsc[f] = __uint_as_float(__builtin_amdgcn_readlane(__float_as_uint(hj), f));
      }
    }
  }

  // FC + softmax (all lanes redundant from uniform h; lane 0 writes)
  float logits[C_];
#pragma unroll
  for (int c = 0; c < C_; ++c) {
    float aa = bfc[c];
#pragma unroll
    for (int f = 0; f < 32; ++f) aa += hsc[f] * Wfc[f * C_ + c];
    logits[c] = aa;
  }
  if (lane == 0) {
    float mx = logits[0];
#pragma unroll
    for (int c = 1; c < C_; ++c) mx = fmaxf(mx, logits[c]);
    float e[C_], sden = 0.f;
#pragma unroll
    for (int c = 0; c < C_; ++c) { e[c] = __expf(logits[c] - mx); sden += e[c]; }
    const float rs = 1.f / sden;
#pragma unroll
    for (int c = 0; c < C_; ++c) out[(size_t)row * C_ + c] = e[c] * rs;
  }
}

// ---------------------------------------------------------------------------
extern "C" void kernel_launch(void* const* d_in, const int* in_sizes, int n_in,
                              void* d_out, int out_size, void* d_ws, size_t ws_size,
                              hipStream_t stream) {
  const float* x   = (const float*)d_in[0];
  const float* Wx  = (const float*)d_in[1];
  const float* Wh  = (const float*)d_in[2];
  const float* bv  = (const float*)d_in[3];
  const float* Wfc = (const float*)d_in[4];
  const float* bfc = (const float*)d_in[5];
  float* out = (float*)d_out;

  k_fused<<<B_, 320, 0, stream>>>(x, Wx, bv, Wh, Wfc, bfc, out);
}